// Round 1
// baseline (125.042 us; speedup 1.0000x reference)
//
#include <hip/hip_runtime.h>

#define N_QUERY 100000
#define NSAMPLE 16
#define C 64

// 16 lanes per query; lane t owns channels [4t, 4t+4).
// Wave of 64 = 4 queries. Each lane preloads one neighbor index and
// broadcasts via __shfl within its 16-lane group.
__global__ __launch_bounds__(256) void KnnPooling_kernel(
    const float* __restrict__ feat,
    const int* __restrict__ idx,
    float* __restrict__ out) {

    int gtid = blockIdx.x * blockDim.x + threadIdx.x;
    int m = gtid >> 4;       // query id
    int t = gtid & 15;       // float4 channel group
    if (m >= N_QUERY) return;

    // coalesced idx load: 16 lanes read the 16 neighbors of query m
    int my_idx = idx[m * NSAMPLE + t];

    int lane = threadIdx.x & 63;
    int group_base = lane & 48;   // first lane of this 16-lane group

    float4 acc = make_float4(-INFINITY, -INFINITY, -INFINITY, -INFINITY);

    #pragma unroll
    for (int j = 0; j < NSAMPLE; ++j) {
        int nj = __shfl(my_idx, group_base + j, 64);
        const float4* row = (const float4*)(feat + (long long)nj * C);
        float4 v = row[t];
        acc.x = fmaxf(acc.x, v.x);
        acc.y = fmaxf(acc.y, v.y);
        acc.z = fmaxf(acc.z, v.z);
        acc.w = fmaxf(acc.w, v.w);
    }

    ((float4*)out)[m * 16 + t] = acc;
}

extern "C" void kernel_launch(void* const* d_in, const int* in_sizes, int n_in,
                              void* d_out, int out_size, void* d_ws, size_t ws_size,
                              hipStream_t stream) {
    const float* feat = (const float*)d_in[0];
    const int* idx = (const int*)d_in[1];
    float* out = (float*)d_out;

    int total_threads = N_QUERY * 16;           // 1.6M
    int block = 256;
    int grid = (total_threads + block - 1) / block;  // 6250
    KnnPooling_kernel<<<grid, block, 0, stream>>>(feat, idx, out);
}

// Round 2
// 123.374 us; speedup vs baseline: 1.0135x; 1.0135x over previous
//
#include <hip/hip_runtime.h>

#define N_QUERY 100000
#define NSAMPLE 16
#define C 64

// 16 lanes per query; lane t owns channels [4t, 4t+4).
// Wave of 64 = 4 queries. Each lane preloads one neighbor index and
// broadcasts via __shfl within its 16-lane group.
//
// R1 change: gather loads batched 8-deep into a register array before the
// max-reduce consumes them -> ~8 outstanding float4 loads per wave instead of
// the ~4 the compiler scheduled at 36 VGPR. Latency-hiding, not BW, is the
// bottleneck (VALUBusy 5.8%, hbm 45% peak at R0).
__global__ __launch_bounds__(256) void KnnPooling_kernel(
    const float* __restrict__ feat,
    const int* __restrict__ idx,
    float* __restrict__ out) {

    int gtid = blockIdx.x * blockDim.x + threadIdx.x;
    int m = gtid >> 4;       // query id
    int t = gtid & 15;       // float4 channel group
    if (m >= N_QUERY) return;

    // coalesced idx load: 16 lanes read the 16 neighbors of query m
    int my_idx = idx[m * NSAMPLE + t];

    int lane = threadIdx.x & 63;
    int group_base = lane & 48;   // first lane of this 16-lane group

    float4 acc0 = make_float4(-INFINITY, -INFINITY, -INFINITY, -INFINITY);
    float4 acc1 = make_float4(-INFINITY, -INFINITY, -INFINITY, -INFINITY);

    float4 v[8];

    // batch 1: neighbors 0..7 — issue all 8 loads, then reduce
    #pragma unroll
    for (int j = 0; j < 8; ++j) {
        int nj = __shfl(my_idx, group_base + j, 64);
        v[j] = ((const float4*)(feat + (long long)nj * C))[t];
    }
    #pragma unroll
    for (int j = 0; j < 8; ++j) {
        float4& a = (j & 1) ? acc1 : acc0;
        a.x = fmaxf(a.x, v[j].x);
        a.y = fmaxf(a.y, v[j].y);
        a.z = fmaxf(a.z, v[j].z);
        a.w = fmaxf(a.w, v[j].w);
    }

    // batch 2: neighbors 8..15
    #pragma unroll
    for (int j = 0; j < 8; ++j) {
        int nj = __shfl(my_idx, group_base + 8 + j, 64);
        v[j] = ((const float4*)(feat + (long long)nj * C))[t];
    }
    #pragma unroll
    for (int j = 0; j < 8; ++j) {
        float4& a = (j & 1) ? acc1 : acc0;
        a.x = fmaxf(a.x, v[j].x);
        a.y = fmaxf(a.y, v[j].y);
        a.z = fmaxf(a.z, v[j].z);
        a.w = fmaxf(a.w, v[j].w);
    }

    float4 acc;
    acc.x = fmaxf(acc0.x, acc1.x);
    acc.y = fmaxf(acc0.y, acc1.y);
    acc.z = fmaxf(acc0.z, acc1.z);
    acc.w = fmaxf(acc0.w, acc1.w);

    ((float4*)out)[m * 16 + t] = acc;
}

extern "C" void kernel_launch(void* const* d_in, const int* in_sizes, int n_in,
                              void* d_out, int out_size, void* d_ws, size_t ws_size,
                              hipStream_t stream) {
    const float* feat = (const float*)d_in[0];
    const int* idx = (const int*)d_in[1];
    float* out = (float*)d_out;

    int total_threads = N_QUERY * 16;           // 1.6M
    int block = 256;
    int grid = (total_threads + block - 1) / block;  // 6250
    KnnPooling_kernel<<<grid, block, 0, stream>>>(feat, idx, out);
}